// Round 8
// baseline (267.321 us; speedup 1.0000x reference)
//
#include <hip/hip_runtime.h>
#include <hip/hip_bf16.h>

#define B_     32
#define NL     256
#define NH     16
#define DIN    16
#define DOUT   32
#define KK     8
#define DD     512
#define LPB    8           // l's per block
#define BG     2           // b's per block (packed into MFMA M)
#define PSTR   24          // xs LDS row stride in shorts (16 data + 8 pad)

typedef __attribute__((ext_vector_type(8)))  short sh8;
typedef __attribute__((ext_vector_type(16))) float f32x16;

__device__ __forceinline__ short f2b(float f) {   // fp32->bf16 RNE
    union { float f; unsigned u; } x; x.f = f;
    unsigned r = (x.u + 0x7FFFu + ((x.u >> 16) & 1u)) >> 16;
    return (short)r;
}
__device__ __forceinline__ float b2f(short s) {
    union { unsigned u; float f; } x; x.u = ((unsigned)(unsigned short)s) << 16;
    return x.f;
}
__device__ __forceinline__ void split3(float f, short& h, short& m, short& l) {
    h = f2b(f); float r1 = f - b2f(h);
    m = f2b(r1); float r2 = r1 - b2f(m);
    l = f2b(r2);
}

// acc += (a0+a1+a2)*(b0+b1+b2) to ~2^-24, 32x32x16
#define MFMA6_32(acc, a0, a1, a2, b0, b1, b2)                                  \
    acc = __builtin_amdgcn_mfma_f32_32x32x16_bf16(a0, b0, acc, 0, 0, 0);       \
    acc = __builtin_amdgcn_mfma_f32_32x32x16_bf16(a0, b1, acc, 0, 0, 0);       \
    acc = __builtin_amdgcn_mfma_f32_32x32x16_bf16(a1, b0, acc, 0, 0, 0);       \
    acc = __builtin_amdgcn_mfma_f32_32x32x16_bf16(a0, b2, acc, 0, 0, 0);       \
    acc = __builtin_amdgcn_mfma_f32_32x32x16_bf16(a1, b1, acc, 0, 0, 0);       \
    acc = __builtin_amdgcn_mfma_f32_32x32x16_bf16(a2, b0, acc, 0, 0, 0);

// tmp2[l,h,i,o] = sum_k alpha*W -> split3, transposed layout [l,h][o*16+i]
__global__ __launch_bounds__(512)
void tmp2_kernel(const float* __restrict__ W, const float* __restrict__ alpha,
                 short* __restrict__ p0, short* __restrict__ p1, short* __restrict__ p2) {
    const int lh = blockIdx.x, d = threadIdx.x;     // d = i*32+o
    const float* a = alpha + lh * KK;
    float acc = 0.f;
#pragma unroll
    for (int k = 0; k < KK; ++k) acc = fmaf(a[k], W[k * DD + d], acc);
    short h, m, l; split3(acc, h, m, l);
    const size_t tt = (size_t)lh * DD + (d & 31) * 16 + (d >> 5);
    p0[tt] = h; p1[tt] = m; p2[tt] = l;
}

// squash s -> v. MODE 0: scale 1/16 -> vbuf. MODE 1: -> vbuf. MODE 2: -> out.
template <int MODE>
__global__ __launch_bounds__(64)
void reduce_kernel(const float* __restrict__ s, float* __restrict__ vbuf,
                   float* __restrict__ out_v, float* __restrict__ out_a) {
    const int bh = blockIdx.x, t = threadIdx.x;
    const float cs = (MODE == 0) ? (1.0f / 16.0f) : 1.0f;
    const float* sp = s + (size_t)bh * DD + t * 8;
    float v[8];
#pragma unroll
    for (int j = 0; j < 8; ++j) v[j] = sp[j] * cs;
    float sq = 0.f;
#pragma unroll
    for (int j = 0; j < 8; ++j) sq = fmaf(v[j], v[j], sq);
#pragma unroll
    for (int mm = 1; mm < 64; mm <<= 1) sq += __shfl_xor(sq, mm, 64);
    const float scale = sq / (1.0f + sq);
    const float inv   = scale / sqrtf(sq + 1e-11f);
    float* po = (MODE == 2) ? (out_v + (size_t)bh * DD + t * 8)
                            : (vbuf + (size_t)bh * DD + t * 8);
#pragma unroll
    for (int j = 0; j < 8; ++j) po[j] = v[j] * inv;
    if (MODE == 2 && t == 0) out_a[bh] = scale;
}

// Block = (b-pair, l-chunk of 8). 512 thr = 8 waves; wave w owns h = 2w, 2w+1.
// Per (l,h): P(2b x 16r x 32o) = one MFMA6 (32x32x16, M = b'*16+r, K = i).
// MODE 0: sacc += P. MODE!=0: dots -> 1 barrier -> wave-local softmax -> sacc += c*P.
template <int MODE>
__global__ __launch_bounds__(512)
void pass_kernel(const float* __restrict__ x,
                 const short* __restrict__ t0, const short* __restrict__ t1,
                 const short* __restrict__ t2p,
                 const float* __restrict__ vbuf, float* __restrict__ blog,
                 float* __restrict__ snext) {
    __shared__ __align__(16) short xs0[BG * LPB * 16 * PSTR];   // 12 KB each
    __shared__ __align__(16) short xs1[BG * LPB * 16 * PSTR];
    __shared__ __align__(16) short xs2[BG * LPB * 16 * PSTR];
    __shared__ float dotsL[2][2][16];                            // [parity][bq][h]

    const int t  = threadIdx.x;
    const int bg = blockIdx.x >> 5, lc = blockIdx.x & 31;
    const int b0 = bg * BG, l0 = lc * LPB;
    const int wv = t >> 6, lane = t & 63;
    const int o  = lane & 31, l5 = lane >> 5;
    const int i0 = l5 * 8;

    // ---- stage x -> split3 padded LDS: xs[(b'*LPB+l)*16+r][PSTR] ----
    {
        const int ih = t & 1, row = t >> 1;          // row 0..255
        const int p = row >> 4, r = row & 15;        // p = b'*LPB + l
        const float* xg = x + ((size_t)(b0 + (p >> 3)) * NL + l0 + (p & 7)) * 256
                            + r * 16 + ih * 8;
        float xv[8];
        *(float4*)&xv[0] = *(const float4*)&xg[0];
        *(float4*)&xv[4] = *(const float4*)&xg[4];
        sh8 v0, v1, v2;
#pragma unroll
        for (int j = 0; j < 8; ++j) {
            short h_, m_, l_; split3(xv[j], h_, m_, l_);
            v0[j] = h_; v1[j] = m_; v2[j] = l_;
        }
        const int la = row * PSTR + ih * 8;
        *(sh8*)&xs0[la] = v0; *(sh8*)&xs1[la] = v1; *(sh8*)&xs2[la] = v2;
    }
    __syncthreads();

    // ---- v preload (fp32 regs): vr[hh][bq][j], C-row rr = (j&3)+8*((j>>2)&1)+4*l5 ----
    float vr[2][2][8];
    if (MODE != 0) {
#pragma unroll
        for (int hh = 0; hh < 2; ++hh) {
            const int h = wv * 2 + hh;
#pragma unroll
            for (int bq = 0; bq < 2; ++bq) {
                const float* vp = vbuf + ((size_t)(b0 + bq) * NH + h) * DD;
#pragma unroll
                for (int j = 0; j < 8; ++j) {
                    const int rr = (j & 3) + 8 * ((j >> 2) & 1) + 4 * l5;
                    vr[hh][bq][j] = vp[rr * 32 + o];
                }
            }
        }
    }

    f32x16 sacc[2];
#pragma unroll
    for (int hh = 0; hh < 2; ++hh)
#pragma unroll
        for (int j = 0; j < 16; ++j) sacc[hh][j] = 0.f;

    const int aoff0 = ((lane >> 4) & 1) * (LPB * 16 * PSTR) + (lane & 15) * PSTR + i0;

    for (int l = 0; l < LPB; ++l) {
        const int lg = l0 + l;
        const int par = l & 1;

        // blog prefetch (MODE 2): issued early, consumed after barrier
        float blg = 0.f;
        if (MODE == 2 && lane < 32)
            blg = blog[((size_t)(b0 + (lane >> 4)) * NL + lg) * NH + (lane & 15)];

        const int ao = aoff0 + l * (16 * PSTR);
        const sh8 a0 = *(const sh8*)&xs0[ao];
        const sh8 a1 = *(const sh8*)&xs1[ao];
        const sh8 a2 = *(const sh8*)&xs2[ao];

        if (MODE != 0) {
            f32x16 P[2];
#pragma unroll
            for (int hh = 0; hh < 2; ++hh) {
                const int h = wv * 2 + hh;
                const size_t tb = ((size_t)lg * NH + h) * DD + o * 16 + i0;
                const sh8 b0f = *(const sh8*)(t0 + tb);
                const sh8 b1f = *(const sh8*)(t1 + tb);
                const sh8 b2f_ = *(const sh8*)(t2p + tb);
                f32x16 acc;
#pragma unroll
                for (int j = 0; j < 16; ++j) acc[j] = 0.f;
                MFMA6_32(acc, a0, a1, a2, b0f, b1f, b2f_)
                P[hh] = acc;
                float d0 = 0.f, d1 = 0.f;
#pragma unroll
                for (int j = 0; j < 8; ++j) d0 = fmaf(P[hh][j], vr[hh][0][j], d0);
#pragma unroll
                for (int j = 0; j < 8; ++j) d1 = fmaf(P[hh][8 + j], vr[hh][1][j], d1);
#pragma unroll
                for (int mm = 1; mm < 64; mm <<= 1) {
                    d0 += __shfl_xor(d0, mm, 64);
                    d1 += __shfl_xor(d1, mm, 64);
                }
                if (lane == 0) { dotsL[par][0][h] = d0; dotsL[par][1][h] = d1; }
            }
            __syncthreads();        // dotsL[par] published (single barrier per l)

            // ---- wave-local softmax (redundant per wave, no 2nd barrier) ----
            float c00, c01, c10, c11;
            {
                const int bq = lane >> 4, hq = lane & 15;
                float d = 0.f;
                if (lane < 32) {
                    d = dotsL[par][bq][hq];
                    if (MODE == 2) d += blg;
                    if (MODE == 1 && wv == 0)
                        blog[((size_t)(b0 + bq) * NL + lg) * NH + hq] = d;
                }
                float mx = d;
#pragma unroll
                for (int mm = 1; mm < 16; mm <<= 1) mx = fmaxf(mx, __shfl_xor(mx, mm, 16));
                const float e = __expf(d - mx);
                float sm = e;
#pragma unroll
                for (int mm = 1; mm < 16; mm <<= 1) sm += __shfl_xor(sm, mm, 16);
                const float cv = e / sm;           // valid in lanes 0..31
                c00 = __shfl(cv, wv * 2, 64);
                c01 = __shfl(cv, wv * 2 + 1, 64);
                c10 = __shfl(cv, 16 + wv * 2, 64);
                c11 = __shfl(cv, 16 + wv * 2 + 1, 64);
            }
#pragma unroll
            for (int j = 0; j < 8; ++j) {
                sacc[0][j]     = fmaf(c00, P[0][j],     sacc[0][j]);
                sacc[0][8 + j] = fmaf(c10, P[0][8 + j], sacc[0][8 + j]);
                sacc[1][j]     = fmaf(c01, P[1][j],     sacc[1][j]);
                sacc[1][8 + j] = fmaf(c11, P[1][8 + j], sacc[1][8 + j]);
            }
        } else {
#pragma unroll
            for (int hh = 0; hh < 2; ++hh) {
                const int h = wv * 2 + hh;
                const size_t tb = ((size_t)lg * NH + h) * DD + o * 16 + i0;
                const sh8 b0f = *(const sh8*)(t0 + tb);
                const sh8 b1f = *(const sh8*)(t1 + tb);
                const sh8 b2f_ = *(const sh8*)(t2p + tb);
                MFMA6_32(sacc[hh], a0, a1, a2, b0f, b1f, b2f_)
            }
        }
    }

    // ---- epilogue: atomic accumulate s[b][h][d], d = rr*32 + o ----
#pragma unroll
    for (int hh = 0; hh < 2; ++hh) {
        const int h = wv * 2 + hh;
#pragma unroll
        for (int j = 0; j < 16; ++j) {
            const int bq = j >> 3;
            const int rr = (j & 3) + 8 * ((j >> 2) & 1) + 4 * l5;
            atomicAdd(&snext[((size_t)(b0 + bq) * NH + h) * DD + rr * 32 + o], sacc[hh][j]);
        }
    }
}

extern "C" void kernel_launch(void* const* d_in, const int* in_sizes, int n_in,
                              void* d_out, int out_size, void* d_ws, size_t ws_size,
                              hipStream_t stream) {
    const float* x     = (const float*)d_in[0];
    // d_in[1] = adj (unused by forward)
    const float* W     = (const float*)d_in[2];
    const float* alpha = (const float*)d_in[3];
    float* out   = (float*)d_out;
    float* out_v = out;                          // B*NH*DD
    float* out_a = out + (size_t)B_ * NH * DD;   // B*NH

    char* base = (char*)d_ws;
    size_t off = 0;
    short* t0   = (short*)(base + off); off += (size_t)NL * NH * DD * 2;   // 4 MB
    short* t1   = (short*)(base + off); off += (size_t)NL * NH * DD * 2;   // 4 MB
    short* t2p  = (short*)(base + off); off += (size_t)NL * NH * DD * 2;   // 4 MB
    float* s0   = (float*)(base + off); off += (size_t)B_ * NH * DD * 4;   // 1 MB
    float* s1   = (float*)(base + off); off += (size_t)B_ * NH * DD * 4;   // 1 MB
    float* vbuf = (float*)(base + off); off += (size_t)B_ * NH * DD * 4;   // 1 MB
    float* blogp= (float*)(base + off); off += (size_t)B_ * NL * NH * 4;   // 0.5 MB -> 15.5 MB

    hipMemsetAsync(s0, 0, (size_t)2 * B_ * NH * DD * 4, stream);   // s0 + s1

    tmp2_kernel<<<NL * NH, 512, 0, stream>>>(W, alpha, t0, t1, t2p);

    const int grid = (B_ / BG) * (NL / LPB);   // 512
    pass_kernel<0><<<grid, 512, 0, stream>>>(x, t0, t1, t2p, vbuf, blogp, s0);
    reduce_kernel<0><<<B_ * NH, 64, 0, stream>>>(s0, vbuf, nullptr, nullptr);

    pass_kernel<1><<<grid, 512, 0, stream>>>(x, t0, t1, t2p, vbuf, blogp, s1);
    reduce_kernel<1><<<B_ * NH, 64, 0, stream>>>(s1, vbuf, nullptr, nullptr);

    hipMemsetAsync(s0, 0, (size_t)B_ * NH * DD * 4, stream);       // reuse as s2

    pass_kernel<2><<<grid, 512, 0, stream>>>(x, t0, t1, t2p, vbuf, blogp, s0);
    reduce_kernel<2><<<B_ * NH, 64, 0, stream>>>(s0, nullptr, out_v, out_a);
}

// Round 9
// 227.749 us; speedup vs baseline: 1.1738x; 1.1738x over previous
//
#include <hip/hip_runtime.h>
#include <hip/hip_bf16.h>

#define B_     32
#define NL     256
#define NH     16
#define DD     512
#define KK     8
#define LPB    32          // l's per block
#define NLC    (NL / LPB)  // 8 spart slots
#define CHUNK  4           // l's per softmax barrier
#define PSTR   24          // xs row stride in f16 (16 data + 8 pad = 48 B)

typedef _Float16 f16;
typedef __attribute__((ext_vector_type(8)))  f16   f16x8;
typedef __attribute__((ext_vector_type(16))) float f32x16;

#define LO_SCALE 1024.0f
#define LO_INV   (1.0f / 1024.0f)

// fp32 -> fp16 hi + scaled lo (lo = (f-hi)*1024, avoids fp16 denormals)
__device__ __forceinline__ void split2s(float f, f16& h, f16& l) {
    h = (f16)f;
    l = (f16)((f - (float)h) * LO_SCALE);
}

// tmp2[l,h,i,o] = sum_k alpha*W -> fp16 hi/lo-scaled, transposed [l,h][o*16+i]
__global__ __launch_bounds__(512)
void tmp2_kernel(const float* __restrict__ W, const float* __restrict__ alpha,
                 f16* __restrict__ t2h, f16* __restrict__ t2l) {
    const int lh = blockIdx.x, d = threadIdx.x;     // d = i*32+o
    const float* a = alpha + lh * KK;
    float acc = 0.f;
#pragma unroll
    for (int k = 0; k < KK; ++k) acc = fmaf(a[k], W[k * DD + d], acc);
    f16 h, l; split2s(acc, h, l);
    const size_t tt = (size_t)lh * DD + (d & 31) * 16 + (d >> 5);
    t2h[tt] = h; t2l[tt] = l;
}

// deterministic fixed-order sum of 8 spart slots + squash.
// MODE 0: *1/16 -> vbuf. MODE 1: -> vbuf. MODE 2: -> out.
template <int MODE>
__global__ __launch_bounds__(64)
void reduce_kernel(const float* __restrict__ spart, float* __restrict__ vbuf,
                   float* __restrict__ out_v, float* __restrict__ out_a) {
    const int bh = blockIdx.x, t = threadIdx.x;
    const float cs = (MODE == 0) ? (1.0f / 16.0f) : 1.0f;
    float acc[8];
#pragma unroll
    for (int j = 0; j < 8; ++j) acc[j] = 0.f;
    for (int ls = 0; ls < NLC; ++ls) {              // fixed order (determinism)
        const float* p = spart + ((size_t)ls * (B_ * NH) + bh) * DD + t * 8;
        const float4 u0 = *(const float4*)&p[0];
        const float4 u1 = *(const float4*)&p[4];
        acc[0] += u0.x; acc[1] += u0.y; acc[2] += u0.z; acc[3] += u0.w;
        acc[4] += u1.x; acc[5] += u1.y; acc[6] += u1.z; acc[7] += u1.w;
    }
#pragma unroll
    for (int j = 0; j < 8; ++j) acc[j] *= cs;
    float sq = 0.f;
#pragma unroll
    for (int j = 0; j < 8; ++j) sq = fmaf(acc[j], acc[j], sq);
#pragma unroll
    for (int mm = 1; mm < 64; mm <<= 1) sq += __shfl_xor(sq, mm, 64);
    const float scale = sq / (1.0f + sq);
    const float inv   = scale / sqrtf(sq + 1e-11f);
    float* po = (MODE == 2) ? (out_v + (size_t)bh * DD + t * 8)
                            : (vbuf + (size_t)bh * DD + t * 8);
#pragma unroll
    for (int j = 0; j < 8; ++j) po[j] = acc[j] * inv;
    if (MODE == 2 && t == 0) out_a[bh] = scale;
}

// Block = (b, lc of 32 l). 512 thr = 8 waves; wave w owns h = 2w, 2w+1.
// Per (l,h): P(16r x 32o) via 3 independent 32x32x16_f16 MFMAs (M rows 16-31 dup/unused):
//   P = c00 + (c01 + c10)/1024. MODE!=0: dots(P,v) -> chunked softmax -> sacc += c*P.
// Epilogue: PLAIN stores to spart[lc][b][h][:] (no atomics).
template <int MODE>
__global__ __launch_bounds__(512)
void pass_kernel(const float* __restrict__ x,
                 const f16* __restrict__ t2h, const f16* __restrict__ t2l,
                 const float* __restrict__ vbuf, float* __restrict__ blog,
                 float* __restrict__ spart) {
    __shared__ __align__(16) f16 xsh[LPB * 16 * PSTR];   // 24 KB
    __shared__ __align__(16) f16 xsl[LPB * 16 * PSTR];   // 24 KB
    __shared__ float dotsL[2][CHUNK][16];

    const int t  = threadIdx.x;
    const int b  = blockIdx.x >> 3, lc = blockIdx.x & 7;   // XCD = lc -> t2 slice L2-resident
    const int l0 = lc * LPB;
    const int wv = t >> 6, lane = t & 63;
    const int o  = lane & 31, l5 = lane >> 5;
    const int i0 = l5 * 8;
    const int rA = lane & 15;        // A row (rows 16-31 duplicate rows 0-15; P[8..15] unused)

    // ---- stage x -> fp16 hi/lo-scaled LDS: xs[(l*16+r)*PSTR + i] ----
    {
        const int l = t >> 4, r = t & 15;
        const float* xg = x + ((size_t)b * NL + l0 + l) * 256 + r * 16;
        float xv[16];
#pragma unroll
        for (int q = 0; q < 4; ++q) *(float4*)&xv[q * 4] = *(const float4*)&xg[q * 4];
        f16 hi[16], lo[16];
#pragma unroll
        for (int j = 0; j < 16; ++j) split2s(xv[j], hi[j], lo[j]);
        const int la = t * PSTR;
        *(f16x8*)&xsh[la]     = *(f16x8*)&hi[0];
        *(f16x8*)&xsh[la + 8] = *(f16x8*)&hi[8];
        *(f16x8*)&xsl[la]     = *(f16x8*)&lo[0];
        *(f16x8*)&xsl[la + 8] = *(f16x8*)&lo[8];
    }
    __syncthreads();

    // ---- v preload: vr[hh][j] = v[b,h, rr(j)*32+o], rr = (j&3)+8*(j>>2)+4*l5 ----
    float vr[2][8];
    if (MODE != 0) {
#pragma unroll
        for (int hh = 0; hh < 2; ++hh) {
            const float* vp = vbuf + ((size_t)b * NH + (wv * 2 + hh)) * DD;
#pragma unroll
            for (int j = 0; j < 8; ++j) {
                const int rr = (j & 3) + 8 * (j >> 2) + 4 * l5;
                vr[hh][j] = vp[rr * 32 + o];
            }
        }
    }

    float sacc[2][8];
#pragma unroll
    for (int hh = 0; hh < 2; ++hh)
#pragma unroll
        for (int j = 0; j < 8; ++j) sacc[hh][j] = 0.f;

    for (int ch = 0; ch < LPB / CHUNK; ++ch) {
        const int par = ch & 1;
        float blg = 0.f;
        if (MODE == 2)
            blg = blog[((size_t)b * NL + l0 + ch * CHUNK + (lane >> 4)) * NH + (lane & 15)];

        float Pst[CHUNK][2][8];
#pragma unroll
        for (int lq = 0; lq < CHUNK; ++lq) {
            const int l = ch * CHUNK + lq;
            const int la = (l * 16 + rA) * PSTR + i0;
            const f16x8 a0 = *(const f16x8*)&xsh[la];
            const f16x8 a1 = *(const f16x8*)&xsl[la];
#pragma unroll
            for (int hh = 0; hh < 2; ++hh) {
                const int h = wv * 2 + hh;
                const size_t tb = ((size_t)(l0 + l) * NH + h) * DD + o * 16 + i0;
                const f16x8 b0 = *(const f16x8*)(t2h + tb);
                const f16x8 b1 = *(const f16x8*)(t2l + tb);
                f32x16 z;
#pragma unroll
                for (int j = 0; j < 16; ++j) z[j] = 0.f;
                f32x16 c00 = __builtin_amdgcn_mfma_f32_32x32x16_f16(a0, b0, z, 0, 0, 0);
                f32x16 c01 = __builtin_amdgcn_mfma_f32_32x32x16_f16(a0, b1, z, 0, 0, 0);
                f32x16 c10 = __builtin_amdgcn_mfma_f32_32x32x16_f16(a1, b0, z, 0, 0, 0);
                float d0 = 0.f;
#pragma unroll
                for (int j = 0; j < 8; ++j) {
                    const float pj = fmaf(c01[j] + c10[j], LO_INV, c00[j]);
                    if (MODE != 0) { Pst[lq][hh][j] = pj; d0 = fmaf(pj, vr[hh][j], d0); }
                    else           sacc[hh][j] += pj;
                }
                if (MODE != 0) {
#pragma unroll
                    for (int mm = 1; mm < 64; mm <<= 1) d0 += __shfl_xor(d0, mm, 64);
                    if (lane == 0) dotsL[par][lq][h] = d0;
                }
            }
        }

        if (MODE != 0) {
            __syncthreads();           // dotsL[par] published (1 barrier per chunk)
            // wave-local softmax: lane -> (lq = lane>>4, hq = lane&15)
            float d = dotsL[par][lane >> 4][lane & 15];
            if (MODE == 2) d += blg;
            if (MODE == 1 && wv == 0)
                blog[((size_t)b * NL + l0 + ch * CHUNK + (lane >> 4)) * NH + (lane & 15)] = d;
            float mx = d;
#pragma unroll
            for (int mm = 1; mm < 16; mm <<= 1) mx = fmaxf(mx, __shfl_xor(mx, mm, 16));
            const float e = __expf(d - mx);
            float sm = e;
#pragma unroll
            for (int mm = 1; mm < 16; mm <<= 1) sm += __shfl_xor(sm, mm, 16);
            const float cv = e / sm;
#pragma unroll
            for (int lq = 0; lq < CHUNK; ++lq) {
                const float cA = __shfl(cv, lq * 16 + wv * 2, 64);
                const float cB = __shfl(cv, lq * 16 + wv * 2 + 1, 64);
#pragma unroll
                for (int j = 0; j < 8; ++j) {
                    sacc[0][j] = fmaf(cA, Pst[lq][0][j], sacc[0][j]);
                    sacc[1][j] = fmaf(cB, Pst[lq][1][j], sacc[1][j]);
                }
            }
        }
    }

    // ---- epilogue: plain stores, spart[lc][b][h][rr*32+o] ----
#pragma unroll
    for (int hh = 0; hh < 2; ++hh) {
        float* sp = spart + ((size_t)lc * (B_ * NH) + b * NH + (wv * 2 + hh)) * DD;
#pragma unroll
        for (int j = 0; j < 8; ++j) {
            const int rr = (j & 3) + 8 * (j >> 2) + 4 * l5;
            sp[rr * 32 + o] = sacc[hh][j];
        }
    }
}

extern "C" void kernel_launch(void* const* d_in, const int* in_sizes, int n_in,
                              void* d_out, int out_size, void* d_ws, size_t ws_size,
                              hipStream_t stream) {
    const float* x     = (const float*)d_in[0];
    // d_in[1] = adj (unused by forward)
    const float* W     = (const float*)d_in[2];
    const float* alpha = (const float*)d_in[3];
    float* out   = (float*)d_out;
    float* out_v = out;                          // B*NH*DD
    float* out_a = out + (size_t)B_ * NH * DD;   // B*NH

    char* base = (char*)d_ws;
    size_t off = 0;
    f16*   t2h   = (f16*)(base + off);   off += (size_t)NL * NH * DD * 2;          // 4 MB
    f16*   t2l   = (f16*)(base + off);   off += (size_t)NL * NH * DD * 2;          // 4 MB
    float* spart = (float*)(base + off); off += (size_t)NLC * B_ * NH * DD * 4;    // 8 MB
    float* vbuf  = (float*)(base + off); off += (size_t)B_ * NH * DD * 4;          // 1 MB
    float* blogp = (float*)(base + off); off += (size_t)B_ * NL * NH * 4;          // 0.5 -> 17.5 MB

    tmp2_kernel<<<NL * NH, 512, 0, stream>>>(W, alpha, t2h, t2l);

    const int grid = B_ * NLC;   // 256
    pass_kernel<0><<<grid, 512, 0, stream>>>(x, t2h, t2l, vbuf, blogp, spart);
    reduce_kernel<0><<<B_ * NH, 64, 0, stream>>>(spart, vbuf, nullptr, nullptr);

    pass_kernel<1><<<grid, 512, 0, stream>>>(x, t2h, t2l, vbuf, blogp, spart);
    reduce_kernel<1><<<B_ * NH, 64, 0, stream>>>(spart, vbuf, nullptr, nullptr);

    pass_kernel<2><<<grid, 512, 0, stream>>>(x, t2h, t2l, vbuf, blogp, spart);
    reduce_kernel<2><<<B_ * NH, 64, 0, stream>>>(spart, nullptr, out_v, out_a);
}

// Round 10
// 162.199 us; speedup vs baseline: 1.6481x; 1.4041x over previous
//
#include <hip/hip_runtime.h>
#include <hip/hip_bf16.h>

#define B_     32
#define NL     256
#define NH     16
#define DD     512
#define KK     8
#define LPB    32          // l's per block
#define NLC    (NL / LPB)  // 8 spart slots
#define CHUNK  4           // l's per softmax barrier
#define PSTR   24          // xs row stride in f16 (16 data + 8 pad = 48 B)

typedef _Float16 f16;
typedef __attribute__((ext_vector_type(8)))  f16   f16x8;
typedef __attribute__((ext_vector_type(16))) float f32x16;

#define LO_SCALE 1024.0f
#define LO_INV   (1.0f / 1024.0f)

// fp32 -> fp16 hi + scaled lo (lo = (f-hi)*1024, avoids fp16 denormals)
__device__ __forceinline__ void split2s(float f, f16& h, f16& l) {
    h = (f16)f;
    l = (f16)((f - (float)h) * LO_SCALE);
}

// tmp2[l,h,i,o] = sum_k alpha*W -> fp16 hi/lo-scaled, transposed [l,h][o*16+i]
__global__ __launch_bounds__(512)
void tmp2_kernel(const float* __restrict__ W, const float* __restrict__ alpha,
                 f16* __restrict__ t2h, f16* __restrict__ t2l) {
    const int lh = blockIdx.x, d = threadIdx.x;     // d = i*32+o
    const float* a = alpha + lh * KK;
    float acc = 0.f;
#pragma unroll
    for (int k = 0; k < KK; ++k) acc = fmaf(a[k], W[k * DD + d], acc);
    f16 h, l; split2s(acc, h, l);
    const size_t tt = (size_t)lh * DD + (d & 31) * 16 + (d >> 5);
    t2h[tt] = h; t2l[tt] = l;
}

// deterministic fixed-order sum of 8 spart slots + squash.
// MODE 0: *1/16 -> vbuf. MODE 1: -> vbuf. MODE 2: -> out.
template <int MODE>
__global__ __launch_bounds__(64)
void reduce_kernel(const float* __restrict__ spart, float* __restrict__ vbuf,
                   float* __restrict__ out_v, float* __restrict__ out_a) {
    const int bh = blockIdx.x, t = threadIdx.x;
    const float cs = (MODE == 0) ? (1.0f / 16.0f) : 1.0f;
    float acc[8];
#pragma unroll
    for (int j = 0; j < 8; ++j) acc[j] = 0.f;
    for (int ls = 0; ls < NLC; ++ls) {              // fixed order (determinism)
        const float* p = spart + ((size_t)ls * (B_ * NH) + bh) * DD + t * 8;
        const float4 u0 = *(const float4*)&p[0];
        const float4 u1 = *(const float4*)&p[4];
        acc[0] += u0.x; acc[1] += u0.y; acc[2] += u0.z; acc[3] += u0.w;
        acc[4] += u1.x; acc[5] += u1.y; acc[6] += u1.z; acc[7] += u1.w;
    }
#pragma unroll
    for (int j = 0; j < 8; ++j) acc[j] *= cs;
    float sq = 0.f;
#pragma unroll
    for (int j = 0; j < 8; ++j) sq = fmaf(acc[j], acc[j], sq);
#pragma unroll
    for (int mm = 1; mm < 64; mm <<= 1) sq += __shfl_xor(sq, mm, 64);
    const float scale = sq / (1.0f + sq);
    const float inv   = scale / sqrtf(sq + 1e-11f);
    float* po = (MODE == 2) ? (out_v + (size_t)bh * DD + t * 8)
                            : (vbuf + (size_t)bh * DD + t * 8);
#pragma unroll
    for (int j = 0; j < 8; ++j) po[j] = acc[j] * inv;
    if (MODE == 2 && t == 0) out_a[bh] = scale;
}

// Block = (b, lc of 32 l). 1024 thr = 16 waves; wave w owns h = w.
// Per (l,h): P(16r x 32o) via 3 independent 32x32x16_f16 MFMAs; P = c00+(c01+c10)/1024.
// t2 for l+1 prefetched into regs during l's compute.
// MODE!=0: dots(P,v) -> chunked softmax (1 barrier/4l) -> sacc += c*P.
// Epilogue: plain stores to spart[lc][b][h][:] (no atomics).
template <int MODE>
__global__ __launch_bounds__(1024)
void pass_kernel(const float* __restrict__ x,
                 const f16* __restrict__ t2h, const f16* __restrict__ t2l,
                 const float* __restrict__ vbuf, float* __restrict__ blog,
                 float* __restrict__ spart) {
    __shared__ __align__(16) f16 xsh[LPB * 16 * PSTR];   // 24 KB
    __shared__ __align__(16) f16 xsl[LPB * 16 * PSTR];   // 24 KB
    __shared__ float dotsL[2][CHUNK][16];

    const int t  = threadIdx.x;
    const int b  = blockIdx.x >> 3, lc = blockIdx.x & 7;   // XCD = lc -> t2 slice locality
    const int l0 = lc * LPB;
    const int wv = t >> 6, lane = t & 63;                  // wv = h
    const int o  = lane & 31, l5 = lane >> 5;
    const int i0 = l5 * 8;
    const int rA = lane & 15;   // A rows 16-31 duplicate 0-15; C regs 8-15 unused

    // ---- stage x -> fp16 hi/lo LDS: xs[(l*16+r)*PSTR + i]; thread = half row ----
    {
        const int row = t >> 1, half = t & 1;   // row = l*16+r
        const float* xg = x + ((size_t)b * NL + l0 + (row >> 4)) * 256
                            + (row & 15) * 16 + half * 8;
        float xv[8];
        *(float4*)&xv[0] = *(const float4*)&xg[0];
        *(float4*)&xv[4] = *(const float4*)&xg[4];
        f16 hi[8], lo[8];
#pragma unroll
        for (int j = 0; j < 8; ++j) split2s(xv[j], hi[j], lo[j]);
        const int la = row * PSTR + half * 8;
        *(f16x8*)&xsh[la] = *(f16x8*)&hi[0];
        *(f16x8*)&xsl[la] = *(f16x8*)&lo[0];
    }
    __syncthreads();

    // ---- v preload: vr[j] = v[b,wv, rr(j)*32+o], rr = (j&3)+8*(j>>2)+4*l5 ----
    float vr[8];
    if (MODE != 0) {
        const float* vp = vbuf + ((size_t)b * NH + wv) * DD;
#pragma unroll
        for (int j = 0; j < 8; ++j) {
            const int rr = (j & 3) + 8 * (j >> 2) + 4 * l5;
            vr[j] = vp[rr * 32 + o];
        }
    }

    // ---- prefetch t2 for l = 0 ----
    f16x8 pf0, pf1;
    {
        const size_t tb = ((size_t)l0 * NH + wv) * DD + o * 16 + i0;
        pf0 = *(const f16x8*)(t2h + tb);
        pf1 = *(const f16x8*)(t2l + tb);
    }

    float sacc[8];
#pragma unroll
    for (int j = 0; j < 8; ++j) sacc[j] = 0.f;

    for (int ch = 0; ch < LPB / CHUNK; ++ch) {
        const int par = ch & 1;
        float blg = 0.f;
        if (MODE == 2)
            blg = blog[((size_t)b * NL + l0 + ch * CHUNK + (lane >> 4)) * NH + (lane & 15)];

        float Pst[CHUNK][8];
#pragma unroll
        for (int lq = 0; lq < CHUNK; ++lq) {
            const int l = ch * CHUNK + lq;
            const int la = (l * 16 + rA) * PSTR + i0;
            const f16x8 a0 = *(const f16x8*)&xsh[la];
            const f16x8 a1 = *(const f16x8*)&xsl[la];
            const f16x8 c0 = pf0, c1 = pf1;
            if (l + 1 < LPB) {      // prefetch next l while computing this one
                const size_t tb = ((size_t)(l0 + l + 1) * NH + wv) * DD + o * 16 + i0;
                pf0 = *(const f16x8*)(t2h + tb);
                pf1 = *(const f16x8*)(t2l + tb);
            }
            f32x16 z;
#pragma unroll
            for (int j = 0; j < 16; ++j) z[j] = 0.f;
            f32x16 c00 = __builtin_amdgcn_mfma_f32_32x32x16_f16(a0, c0, z, 0, 0, 0);
            f32x16 c01 = __builtin_amdgcn_mfma_f32_32x32x16_f16(a0, c1, z, 0, 0, 0);
            f32x16 c10 = __builtin_amdgcn_mfma_f32_32x32x16_f16(a1, c0, z, 0, 0, 0);
            float d0 = 0.f;
#pragma unroll
            for (int j = 0; j < 8; ++j) {
                const float pj = fmaf(c01[j] + c10[j], LO_INV, c00[j]);
                if (MODE != 0) { Pst[lq][j] = pj; d0 = fmaf(pj, vr[j], d0); }
                else           sacc[j] += pj;
            }
            if (MODE != 0) {
#pragma unroll
                for (int mm = 1; mm < 64; mm <<= 1) d0 += __shfl_xor(d0, mm, 64);
                if (lane == 0) dotsL[par][lq][wv] = d0;
            }
        }

        if (MODE != 0) {
            __syncthreads();           // dotsL[par] published (1 barrier per chunk)
            // wave-local softmax: lane -> (lq = lane>>4, hq = lane&15), full chunk per wave
            float d = dotsL[par][lane >> 4][lane & 15];
            if (MODE == 2) d += blg;
            if (MODE == 1 && wv == 0)
                blog[((size_t)b * NL + l0 + ch * CHUNK + (lane >> 4)) * NH + (lane & 15)] = d;
            float mx = d;
#pragma unroll
            for (int mm = 1; mm < 16; mm <<= 1) mx = fmaxf(mx, __shfl_xor(mx, mm, 16));
            const float e = __expf(d - mx);
            float sm = e;
#pragma unroll
            for (int mm = 1; mm < 16; mm <<= 1) sm += __shfl_xor(sm, mm, 16);
            const float cv = e / sm;
#pragma unroll
            for (int lq = 0; lq < CHUNK; ++lq) {
                const float c = __shfl(cv, lq * 16 + wv, 64);
#pragma unroll
                for (int j = 0; j < 8; ++j)
                    sacc[j] = fmaf(c, Pst[lq][j], sacc[j]);
            }
        }
    }

    // ---- epilogue: plain stores, spart[lc][b][wv][rr*32+o] ----
    {
        float* sp = spart + ((size_t)lc * (B_ * NH) + b * NH + wv) * DD;
#pragma unroll
        for (int j = 0; j < 8; ++j) {
            const int rr = (j & 3) + 8 * (j >> 2) + 4 * l5;
            sp[rr * 32 + o] = sacc[j];
        }
    }
}

extern "C" void kernel_launch(void* const* d_in, const int* in_sizes, int n_in,
                              void* d_out, int out_size, void* d_ws, size_t ws_size,
                              hipStream_t stream) {
    const float* x     = (const float*)d_in[0];
    // d_in[1] = adj (unused by forward)
    const float* W     = (const float*)d_in[2];
    const float* alpha = (const float*)d_in[3];
    float* out   = (float*)d_out;
    float* out_v = out;                          // B*NH*DD
    float* out_a = out + (size_t)B_ * NH * DD;   // B*NH

    char* base = (char*)d_ws;
    size_t off = 0;
    f16*   t2h   = (f16*)(base + off);   off += (size_t)NL * NH * DD * 2;          // 4 MB
    f16*   t2l   = (f16*)(base + off);   off += (size_t)NL * NH * DD * 2;          // 4 MB
    float* spart = (float*)(base + off); off += (size_t)NLC * B_ * NH * DD * 4;    // 8 MB
    float* vbuf  = (float*)(base + off); off += (size_t)B_ * NH * DD * 4;          // 1 MB
    float* blogp = (float*)(base + off); off += (size_t)B_ * NL * NH * 4;          // 0.5 -> 17.5 MB

    tmp2_kernel<<<NL * NH, 512, 0, stream>>>(W, alpha, t2h, t2l);

    const int grid = B_ * NLC;   // 256
    pass_kernel<0><<<grid, 1024, 0, stream>>>(x, t2h, t2l, vbuf, blogp, spart);
    reduce_kernel<0><<<B_ * NH, 64, 0, stream>>>(spart, vbuf, nullptr, nullptr);

    pass_kernel<1><<<grid, 1024, 0, stream>>>(x, t2h, t2l, vbuf, blogp, spart);
    reduce_kernel<1><<<B_ * NH, 64, 0, stream>>>(spart, vbuf, nullptr, nullptr);

    pass_kernel<2><<<grid, 1024, 0, stream>>>(x, t2h, t2l, vbuf, blogp, spart);
    reduce_kernel<2><<<B_ * NH, 64, 0, stream>>>(spart, nullptr, out_v, out_a);
}